// Round 17
// baseline (240.422 us; speedup 1.0000x reference)
//
#include <hip/hip_runtime.h>
#include <hip/hip_cooperative_groups.h>

namespace cg = cooperative_groups;

#define N_NODES 50000
#define N_EDGES 800000
#define D_FEAT 64

#define NPART 200                 // edge partitions
#define EPP (N_EDGES / NPART)     // 4000 edges per partition (exact)
#define BIG_SHIFT 9
#define BIG_NODES 512
#define NBIG ((N_NODES + BIG_NODES - 1) / BIG_NODES)  // 98 coarse bins
#define GRID_BUILD 200            // >= NPART work units; co-residency trivially safe

// ================= Fused cooperative CSR build =================
__global__ __launch_bounds__(256, 4) void build_kernel(
    const int* __restrict__ src, const int* __restrict__ dst,
    int* __restrict__ histBB, int* __restrict__ baseBB,
    int* __restrict__ binTot, int* __restrict__ binBase,
    int* __restrict__ offs,
    unsigned int* __restrict__ staging,
    unsigned short* __restrict__ esorted)
{
    cg::grid_group grid = cg::this_grid();
    __shared__ int sa[512];
    __shared__ int sb[512];
    int t = threadIdx.x;

    // ---- P1: per-partition LDS histogram over 98 coarse bins ----
    for (int p = blockIdx.x; p < NPART; p += gridDim.x) {
        if (t < NBIG) sa[t] = 0;
        __syncthreads();
        int base = p * EPP;
        for (int i = t; i < EPP; i += 256)
            atomicAdd(&sa[dst[base + i] >> BIG_SHIFT], 1);
        __syncthreads();
        if (t < NBIG) histBB[p * NBIG + t] = sa[t];
        __syncthreads();
    }
    grid.sync();

    // ---- P2: per-bin exclusive scan over the 200 partitions ----
    for (int bin = blockIdx.x; bin < NBIG; bin += gridDim.x) {
        int v = (t < NPART) ? histBB[t * NBIG + bin] : 0;
        sa[t] = v;
        __syncthreads();
        for (int off = 1; off < 256; off <<= 1) {
            int x = (t >= off) ? sa[t - off] : 0;
            __syncthreads();
            sa[t] += x;
            __syncthreads();
        }
        if (t < NPART) baseBB[t * NBIG + bin] = sa[t] - v;
        if (t == 255) binTot[bin] = sa[255];
        __syncthreads();
    }
    grid.sync();

    // ---- P3: exclusive scan of 98 bin totals (block 0) ----
    if (blockIdx.x == 0) {
        int v = (t < NBIG) ? binTot[t] : 0;
        int lane = t & 63, wave = t >> 6;
        int incl = v;
        #pragma unroll
        for (int o = 1; o < 64; o <<= 1) { int x = __shfl_up(incl, o); if (lane >= o) incl += x; }
        if (lane == 63) sb[wave] = incl;
        __syncthreads();
        int wbase = 0;
        #pragma unroll
        for (int w = 0; w < 4; ++w) wbase += (w < wave) ? sb[w] : 0;
        if (t < NBIG) binBase[t] = wbase + incl - v;
        if (t == NBIG - 1) binBase[NBIG] = wbase + incl;
    }
    grid.sync();

    // ---- P4: scatter packed (src | dstlow<<16), LDS cursors, no global atomics ----
    for (int p = blockIdx.x; p < NPART; p += gridDim.x) {
        if (t < NBIG) sa[t] = binBase[t] + baseBB[p * NBIG + t];
        __syncthreads();
        int base = p * EPP;
        for (int i = t; i < EPP; i += 256) {
            int d = dst[base + i];
            int bin = d >> BIG_SHIFT;
            int pos = atomicAdd(&sa[bin], 1);
            staging[pos] = (unsigned int)src[base + i] |
                           ((unsigned int)(d & (BIG_NODES - 1)) << 16);
        }
        __syncthreads();
    }
    grid.sync();

    // ---- P5: per-bin counting sort, DIRECT global esorted writes ----
    for (int bin = blockIdx.x; bin < NBIG; bin += gridDim.x) {
        int lo = binBase[bin], hi = binBase[bin + 1];
        sa[t] = 0; sa[t + 256] = 0;
        __syncthreads();
        for (int i = lo + t; i < hi; i += 256)
            atomicAdd(&sa[(staging[i] >> 16) & (BIG_NODES - 1)], 1);
        __syncthreads();
        // scan 512 counts with 256 threads: pair + block-scan + expand
        int c0 = sa[2 * t], c1 = sa[2 * t + 1];
        int pv = c0 + c1;
        int lane = t & 63, wave = t >> 6;
        int incl = pv;
        #pragma unroll
        for (int o = 1; o < 64; o <<= 1) { int x = __shfl_up(incl, o); if (lane >= o) incl += x; }
        if (lane == 63) sb[wave] = incl;
        __syncthreads();
        int wbase = 0;
        #pragma unroll
        for (int w = 0; w < 4; ++w) wbase += (w < wave) ? sb[w] : 0;
        int eh = wbase + incl - pv;     // exclusive prefix of the pair
        __syncthreads();                // done reading sb as wave sums
        int e0 = eh, e1 = eh + c0;
        sb[2 * t] = lo + e0;            // global-seeded cursors
        sb[2 * t + 1] = lo + e1;
        int node = (bin << BIG_SHIFT) + 2 * t;
        if (node < N_NODES) offs[node] = lo + e0;
        if (node + 1 < N_NODES) offs[node + 1] = lo + e1;
        if (bin == NBIG - 1 && t == 0) offs[N_NODES] = N_EDGES;
        __syncthreads();
        for (int i = lo + t; i < hi; i += 256) {
            unsigned int pk = staging[i];
            int p = atomicAdd(&sb[(pk >> 16) & (BIG_NODES - 1)], 1);
            esorted[p] = (unsigned short)pk;
        }
        __syncthreads();
    }
}

// ================= K6: high-occupancy CSR pull (unchanged) =================
__global__ __launch_bounds__(256) void csr_pull_kernel(const float* __restrict__ xs,
                                                       const unsigned short* __restrict__ esorted,
                                                       const int* __restrict__ offs,
                                                       float* __restrict__ out) {
    int tid = blockIdx.x * 256 + threadIdx.x;   // grid exactly 50000*16
    int node = tid >> 4;
    int c = tid & 15;
    int beg = offs[node];
    int end = offs[node + 1];
    int deg = end - beg;
    float4 acc = make_float4(0.f, 0.f, 0.f, 0.f);
    for (int j0 = 0; j0 < deg; j0 += 16) {
        int rem = deg - j0;
        int m = rem < 16 ? rem : 16;
        int myid = (c < m) ? (int)__builtin_nontemporal_load(esorted + beg + j0 + c) : 0;
        if (m == 16) {
            #pragma unroll
            for (int k = 0; k < 16; ++k) {
                int s = __shfl(myid, k, 16);
                const float4 v = *reinterpret_cast<const float4*>(xs + s * D_FEAT + c * 4);
                acc.x += v.x; acc.y += v.y; acc.z += v.z; acc.w += v.w;
            }
        } else {
            for (int k = 0; k < m; ++k) {
                int s = __shfl(myid, k, 16);
                const float4 v = *reinterpret_cast<const float4*>(xs + s * D_FEAT + c * 4);
                acc.x += v.x; acc.y += v.y; acc.z += v.z; acc.w += v.w;
            }
        }
    }
    float inv = 1.0f / fmaxf((float)deg, 1.0f);
    float* op = out + (size_t)node * D_FEAT + c * 4;
    __builtin_nontemporal_store(acc.x * inv, op + 0);
    __builtin_nontemporal_store(acc.y * inv, op + 1);
    __builtin_nontemporal_store(acc.z * inv, op + 2);
    __builtin_nontemporal_store(acc.w * inv, op + 3);
}

// ============ Fallback classic build kernels (proven, round 11/13) ============

__global__ __launch_bounds__(1024) void part_hist_kernel(const int* __restrict__ dst,
                                                         int* __restrict__ histBB) {
    __shared__ int h[NBIG];
    int t = threadIdx.x, blk = blockIdx.x;
    if (t < NBIG) h[t] = 0;
    __syncthreads();
    int base = blk * EPP;
    for (int i = t; i < EPP; i += 1024)
        atomicAdd(&h[dst[base + i] >> BIG_SHIFT], 1);
    __syncthreads();
    if (t < NBIG) histBB[blk * NBIG + t] = h[t];
}

__global__ void col_scan_kernel(const int* __restrict__ histBB,
                                int* __restrict__ baseBB,
                                int* __restrict__ binTot) {
    __shared__ int lds[256];
    int bin = blockIdx.x, t = threadIdx.x;
    int v = (t < NPART) ? histBB[t * NBIG + bin] : 0;
    lds[t] = v;
    __syncthreads();
    for (int off = 1; off < 256; off <<= 1) {
        int x = (t >= off) ? lds[t - off] : 0;
        __syncthreads();
        lds[t] += x;
        __syncthreads();
    }
    if (t < NPART) baseBB[t * NBIG + bin] = lds[t] - v;
    if (t == 255) binTot[bin] = lds[255];
}

__global__ void bin_scan_kernel(const int* __restrict__ binTot, int* __restrict__ binBase) {
    __shared__ int wsum[2];
    int t = threadIdx.x;
    int v = (t < NBIG) ? binTot[t] : 0;
    int lane = t & 63, wave = t >> 6;
    int incl = v;
    #pragma unroll
    for (int o = 1; o < 64; o <<= 1) { int x = __shfl_up(incl, o); if (lane >= o) incl += x; }
    if (lane == 63) wsum[wave] = incl;
    __syncthreads();
    int base = (wave == 1) ? wsum[0] : 0;
    if (t < NBIG) binBase[t] = base + incl - v;
    if (t == NBIG - 1) binBase[NBIG] = base + incl;
}

__global__ __launch_bounds__(1024) void part_scatter_kernel(const int* __restrict__ src,
                                                            const int* __restrict__ dst,
                                                            const int* __restrict__ baseBB,
                                                            const int* __restrict__ binBase,
                                                            unsigned int* __restrict__ staging) {
    __shared__ int cur[NBIG];
    int t = threadIdx.x, blk = blockIdx.x;
    if (t < NBIG) cur[t] = binBase[t] + baseBB[blk * NBIG + t];
    __syncthreads();
    int base = blk * EPP;
    for (int i = t; i < EPP; i += 1024) {
        int d = dst[base + i];
        int bin = d >> BIG_SHIFT;
        int pos = atomicAdd(&cur[bin], 1);
        staging[pos] = (unsigned int)src[base + i] |
                       ((unsigned int)(d & (BIG_NODES - 1)) << 16);
    }
}

__global__ __launch_bounds__(512) void sort512_kernel(const unsigned int* __restrict__ staging,
                                                      const int* __restrict__ binBase,
                                                      unsigned short* __restrict__ esorted,
                                                      int* __restrict__ offs) {
    __shared__ int cnt[BIG_NODES];
    __shared__ int cur[BIG_NODES];
    __shared__ int wsum[8];
    int bin = blockIdx.x, t = threadIdx.x;
    int lo = binBase[bin], hi = binBase[bin + 1];
    int nodeLo = bin << BIG_SHIFT;

    cnt[t] = 0;
    __syncthreads();
    for (int i = lo + t; i < hi; i += 512)
        atomicAdd(&cnt[(staging[i] >> 16) & (BIG_NODES - 1)], 1);
    __syncthreads();
    int v = cnt[t];
    int lane = t & 63, wave = t >> 6;
    int incl = v;
    #pragma unroll
    for (int o = 1; o < 64; o <<= 1) { int x = __shfl_up(incl, o); if (lane >= o) incl += x; }
    if (lane == 63) wsum[wave] = incl;
    __syncthreads();
    int wbase = 0;
    #pragma unroll
    for (int w = 0; w < 8; ++w) wbase += (w < wave) ? wsum[w] : 0;
    int excl = wbase + incl - v;
    cur[t] = lo + excl;
    int node = nodeLo + t;
    if (node < N_NODES) offs[node] = lo + excl;
    if (bin == NBIG - 1 && t == 0) offs[N_NODES] = N_EDGES;
    __syncthreads();
    for (int i = lo + t; i < hi; i += 512) {
        unsigned int pk = staging[i];
        int p = atomicAdd(&cur[(pk >> 16) & (BIG_NODES - 1)], 1);
        esorted[p] = (unsigned short)pk;
    }
}

// ---------------- launch ----------------

extern "C" void kernel_launch(void* const* d_in, const int* in_sizes, int n_in,
                              void* d_out, int out_size, void* d_ws, size_t ws_size,
                              hipStream_t stream) {
    const float* xs  = (const float*)d_in[0];
    const int*   src = (const int*)d_in[1];
    const int*   dst = (const int*)d_in[2];
    float* out = (float*)d_out;

    int* ws = (int*)d_ws;
    int* histBB  = ws;                           // NPART*NBIG
    int* baseBB  = histBB + NPART * NBIG;        // NPART*NBIG
    int* binTot  = baseBB + NPART * NBIG;        // NBIG
    int* binBase = binTot + NBIG;                // NBIG+1
    int* offs    = binBase + NBIG + 1;           // N_NODES+1
    unsigned int* staging = (unsigned int*)(offs + N_NODES + 1);      // N_EDGES u32
    unsigned short* esorted = (unsigned short*)(staging + N_EDGES);   // N_EDGES u16

    // Try the fused cooperative build first.
    const int* src_a = src; const int* dst_a = dst;
    int* histBB_a = histBB; int* baseBB_a = baseBB; int* binTot_a = binTot;
    int* binBase_a = binBase; int* offs_a = offs;
    unsigned int* staging_a = staging; unsigned short* esorted_a = esorted;
    void* args[] = { (void*)&src_a, (void*)&dst_a, (void*)&histBB_a, (void*)&baseBB_a,
                     (void*)&binTot_a, (void*)&binBase_a, (void*)&offs_a,
                     (void*)&staging_a, (void*)&esorted_a };
    hipError_t err = hipLaunchCooperativeKernel((const void*)build_kernel,
                                                dim3(GRID_BUILD), dim3(256),
                                                args, 0, stream);
    if (err != hipSuccess) {
        // Classic 5-kernel build (proven path).
        part_hist_kernel<<<NPART, 1024, 0, stream>>>(dst, histBB);
        col_scan_kernel<<<NBIG, 256, 0, stream>>>(histBB, baseBB, binTot);
        bin_scan_kernel<<<1, 128, 0, stream>>>(binTot, binBase);
        part_scatter_kernel<<<NPART, 1024, 0, stream>>>(src, dst, baseBB, binBase, staging);
        sort512_kernel<<<NBIG, 512, 0, stream>>>(staging, binBase, esorted, offs);
    }
    csr_pull_kernel<<<(N_NODES * 16) / 256, 256, 0, stream>>>(xs, esorted, offs, out);
}